// Round 1
// baseline (675.877 us; speedup 1.0000x reference)
//
#include <hip/hip_runtime.h>
#include <hip/hip_bf16.h>

// SingleHeadAttention: B=4, S=4096, D=1024, fp32 in/out, causal, interleaved RoPE.
// Pipeline (all bf16 MFMA, NT GEMMs):
//   cvt x,wq,wk,wv -> bf16 ws
//   Q = X Wq^T (+RoPE epi), K = X Wk^T (+RoPE epi), VT = Wv X^T   [bf16]
//   S = Q K^T * 1/32 (causal tile skip)  [fp32 ws]
//   softmax rows -> P bf16 in place (row stride 8192 bf16)
//   O = P VT^T (k-limited per q-tile)    [fp32 -> d_out]
// ws: full-batch S needs ~409MB, else per-batch S (~208MB) fallback.

#define SEQ 4096
#define DIM 1024
#define NBATCH 4

typedef short bf16x8 __attribute__((ext_vector_type(8)));
typedef float f32x4 __attribute__((ext_vector_type(4)));

__device__ __forceinline__ unsigned short f2bf(float f) {
  unsigned int u = __float_as_uint(f);
  u += 0x7FFFu + ((u >> 16) & 1u);   // RNE
  return (unsigned short)(u >> 16);
}

__global__ __launch_bounds__(256) void cvt_bf16_kernel(const float* __restrict__ in,
                                                       unsigned short* __restrict__ out,
                                                       int n4) {
  int stride = gridDim.x * blockDim.x;
  for (int j = blockIdx.x * blockDim.x + threadIdx.x; j < n4; j += stride) {
    float4 v = ((const float4*)in)[j];
    ushort4 o;
    o.x = f2bf(v.x); o.y = f2bf(v.y); o.z = f2bf(v.z); o.w = f2bf(v.w);
    ((ushort4*)out)[j] = o;
  }
}

// NT GEMM: C[m][n] = sum_k A[m][k] * B[n][k]   (A: M x K, B: N x K, both row-major bf16)
// 128x128 tile, BK=32, 256 threads = 4 waves (2x2), mfma 16x16x32 bf16, 4x4 frags/wave.
// mode: 0 = none, 1 = causal tile skip (scores), 2 = causal k-limit (PV)
// EPI:  0 = RoPE -> bf16, 1 = V^T-layout bf16, 2 = fp32 * scale
template <int EPI>
__global__ __launch_bounds__(256, 2) void gemm_nt_kernel(
    const unsigned short* __restrict__ A,
    const unsigned short* __restrict__ B,
    void* __restrict__ Cv,
    int lda, int ldb, int ldc,
    int K, int nTilesN, long bstrideB,
    int mode, float scale) {
  const int mt = blockIdx.x / nTilesN;
  const int nt = blockIdx.x % nTilesN;
  const int m0 = mt * 128, n0 = nt * 128;
  const int mrow = m0 & (SEQ - 1);                 // row within batch
  if (mode == 1 && n0 > mrow + 127) return;        // fully-masked score tile
  const int Keff = (mode == 2 && mrow + 128 < K) ? (mrow + 128) : K;
  const unsigned short* Bp = B + (long)(m0 >> 12) * bstrideB;  // per-batch B select

  __shared__ unsigned short sA[128 * 32];
  __shared__ unsigned short sB[128 * 32];

  const int t = threadIdx.x;
  const int w = t >> 6, l = t & 63;
  const int wm = w >> 1, wn = w & 1;
  const int srow = l >> 2;            // staging row within 16-row chunk
  const int scol = (l & 3) * 8;       // staging col (8 bf16 = 16B)
  const int frow = l & 15;            // fragment row/col
  const int fk = (l >> 4) * 8;        // fragment k-offset

  f32x4 acc[4][4] = {};

  for (int k0 = 0; k0 < Keff; k0 += 32) {
#pragma unroll
    for (int j = 0; j < 2; ++j) {
      const int c = 2 * w + j;        // 1KiB chunk id (wave-uniform)
      const unsigned short* ga = A + (long)(m0 + c * 16 + srow) * lda + (k0 + scol);
      const unsigned short* gb = Bp + (long)(n0 + c * 16 + srow) * ldb + (k0 + scol);
      __builtin_amdgcn_global_load_lds(
          (const __attribute__((address_space(1))) void*)ga,
          (__attribute__((address_space(3))) void*)(&sA[c * 512]), 16, 0, 0);
      __builtin_amdgcn_global_load_lds(
          (const __attribute__((address_space(1))) void*)gb,
          (__attribute__((address_space(3))) void*)(&sB[c * 512]), 16, 0, 0);
    }
    __syncthreads();
    bf16x8 av[4], bv[4];
#pragma unroll
    for (int i = 0; i < 4; ++i)
      av[i] = *(const bf16x8*)(&sA[(wm * 64 + i * 16 + frow) * 32 + fk]);
#pragma unroll
    for (int i = 0; i < 4; ++i)
      bv[i] = *(const bf16x8*)(&sB[(wn * 64 + i * 16 + frow) * 32 + fk]);
#pragma unroll
    for (int mi = 0; mi < 4; ++mi)
#pragma unroll
      for (int nj = 0; nj < 4; ++nj)
        acc[mi][nj] = __builtin_amdgcn_mfma_f32_16x16x32_bf16(av[mi], bv[nj],
                                                              acc[mi][nj], 0, 0, 0);
    __syncthreads();
  }

  // C/D layout: col = lane&15, row = (lane>>4)*4 + reg   [m89-verified]
  const int rbase = m0 + wm * 64 + (l >> 4) * 4;
  const int cbase = n0 + wn * 64 + frow;

  if (EPI == 2) {
    float* C = (float*)Cv;
#pragma unroll
    for (int mi = 0; mi < 4; ++mi)
#pragma unroll
      for (int nj = 0; nj < 4; ++nj)
#pragma unroll
        for (int r = 0; r < 4; ++r) {
          const int row = rbase + mi * 16 + r;
          const int col = cbase + nj * 16;
          C[(long)row * ldc + col] = acc[mi][nj][r] * scale;
        }
  } else if (EPI == 1) {
    // write C[row=e][col=n] into VT[b][e][s], b=col>>12, s=col&4095
    unsigned short* C = (unsigned short*)Cv;
#pragma unroll
    for (int mi = 0; mi < 4; ++mi)
#pragma unroll
      for (int nj = 0; nj < 4; ++nj)
#pragma unroll
        for (int r = 0; r < 4; ++r) {
          const int row = rbase + mi * 16 + r;
          const int col = cbase + nj * 16;
          const long addr = (long)(col >> 12) * (DIM * SEQ) + (long)row * SEQ + (col & (SEQ - 1));
          C[addr] = f2bf(acc[mi][nj][r]);
        }
  } else {
    // RoPE: pairs (2i,2i+1) are adjacent lanes (col parity == lane parity)
    unsigned short* C = (unsigned short*)Cv;
#pragma unroll
    for (int nj = 0; nj < 4; ++nj) {
      const int col = cbase + nj * 16;
      // inv_freq = 10000^(-(col>>1)/512) ; log2(10000)/512 = 0.025952563241307517
      const float invfreq = exp2f(-0.025952563241307517f * (float)(col >> 1));
      const bool odd = (col & 1) != 0;
#pragma unroll
      for (int mi = 0; mi < 4; ++mi)
#pragma unroll
        for (int r = 0; r < 4; ++r) {
          const int row = rbase + mi * 16 + r;
          const float v = acc[mi][nj][r];
          const float p = __shfl_xor(v, 1, 64);   // partner column (col^1), same row
          const float ang = (float)(row & (SEQ - 1)) * invfreq;
          const float sn = __sinf(ang), cs = __cosf(ang);
          const float outv = odd ? (v * cs + p * sn) : (v * cs - p * sn);
          C[(long)row * ldc + col] = f2bf(outv);
        }
    }
  }
}

// One block per row. Reads fp32 scores (k<=q), stages in LDS, writes P bf16 in place
// (row stride 8192 bf16) with zero pad up to the 128-tile causal edge.
__global__ __launch_bounds__(256) void softmax_kernel(float* __restrict__ S) {
  const int q = blockIdx.x & (SEQ - 1);
  float* row = S + (long)blockIdx.x * SEQ;
  const int len = q + 1;
  const int kpad = (q & ~127) + 128;
  __shared__ float buf[SEQ];
  __shared__ float red[8];
  const int t = threadIdx.x;

  float lmax = -3.0e38f;
  for (int k = t; k < len; k += 256) {
    const float v = row[k];
    buf[k] = v;
    lmax = fmaxf(lmax, v);
  }
#pragma unroll
  for (int o = 32; o; o >>= 1) lmax = fmaxf(lmax, __shfl_xor(lmax, o, 64));
  if ((t & 63) == 0) red[t >> 6] = lmax;
  __syncthreads();
  const float m = fmaxf(fmaxf(red[0], red[1]), fmaxf(red[2], red[3]));

  float lsum = 0.f;
  for (int k = t; k < len; k += 256) lsum += __expf(buf[k] - m);
#pragma unroll
  for (int o = 32; o; o >>= 1) lsum += __shfl_xor(lsum, o, 64);
  if ((t & 63) == 0) red[4 + (t >> 6)] = lsum;
  __syncthreads();
  const float inv = 1.0f / (red[4] + red[5] + red[6] + red[7]);

  unsigned short* prow = (unsigned short*)row;
  for (int k = t; k < len; k += 256) prow[k] = f2bf(__expf(buf[k] - m) * inv);
  for (int k = len + t; k < kpad; k += 256) prow[k] = 0;
}

extern "C" void kernel_launch(void* const* d_in, const int* in_sizes, int n_in,
                              void* d_out, int out_size, void* d_ws, size_t ws_size,
                              hipStream_t stream) {
  (void)in_sizes; (void)n_in; (void)out_size;
  const float* x  = (const float*)d_in[0];
  const float* wq = (const float*)d_in[1];
  const float* wk = (const float*)d_in[2];
  const float* wv = (const float*)d_in[3];
  float* out = (float*)d_out;

  const long NTOK = (long)SEQ * NBATCH;          // 16384
  unsigned short* xb  = (unsigned short*)d_ws;   // [16384][1024] bf16
  unsigned short* wqb = xb + NTOK * DIM;
  unsigned short* wkb = wqb + DIM * DIM;
  unsigned short* wvb = wkb + DIM * DIM;
  unsigned short* Qb  = wvb + DIM * DIM;         // [16384][1024] bf16 (RoPE'd)
  unsigned short* Kb  = Qb + NTOK * DIM;
  unsigned short* VT  = Kb + NTOK * DIM;         // [4][1024][4096] bf16
  float* S = (float*)(VT + NTOK * DIM);          // scores / P

  const size_t base_bytes = 2ull * (4ull * NTOK * DIM + 3ull * DIM * DIM);
  const bool full = ws_size >= base_bytes + 4ull * NBATCH * SEQ * SEQ;

  // --- prep: fp32 -> bf16 ---
  cvt_bf16_kernel<<<2048, 256, 0, stream>>>(x, xb, (int)(NTOK * DIM / 4));
  cvt_bf16_kernel<<<512, 256, 0, stream>>>(wq, wqb, DIM * DIM / 4);
  cvt_bf16_kernel<<<512, 256, 0, stream>>>(wk, wkb, DIM * DIM / 4);
  cvt_bf16_kernel<<<512, 256, 0, stream>>>(wv, wvb, DIM * DIM / 4);

  const int MT_ALL = (int)(NTOK / 128);          // 128
  const float scale = 0.03125f;                  // 1/sqrt(1024)

  // --- projections ---
  gemm_nt_kernel<0><<<MT_ALL * (DIM / 128), 256, 0, stream>>>(
      xb, wqb, Qb, DIM, DIM, DIM, DIM, DIM / 128, 0, 0, 0.f);
  gemm_nt_kernel<0><<<MT_ALL * (DIM / 128), 256, 0, stream>>>(
      xb, wkb, Kb, DIM, DIM, DIM, DIM, DIM / 128, 0, 0, 0.f);
  gemm_nt_kernel<1><<<(DIM / 128) * MT_ALL, 256, 0, stream>>>(
      wvb, xb, VT, DIM, DIM, SEQ, DIM, MT_ALL, 0, 0, 0.f);

  if (full) {
    // S for all 4 batches: [16384][4096] fp32
    gemm_nt_kernel<2><<<MT_ALL * (SEQ / 128), 256, 0, stream>>>(
        Qb, Kb, S, DIM, DIM, SEQ, DIM, SEQ / 128, (long)SEQ * DIM, 1, scale);
    softmax_kernel<<<(int)NTOK, 256, 0, stream>>>(S);
    gemm_nt_kernel<2><<<MT_ALL * (DIM / 128), 256, 0, stream>>>(
        (const unsigned short*)S, VT, out, 2 * SEQ, SEQ, DIM, SEQ, DIM / 128,
        (long)DIM * SEQ, 2, 1.0f);
  } else {
    // per-batch S: [4096][4096] fp32, stream-serialized
    for (int b = 0; b < NBATCH; ++b) {
      const unsigned short* Qp = Qb + (long)b * SEQ * DIM;
      const unsigned short* Kp = Kb + (long)b * SEQ * DIM;
      const unsigned short* Vp = VT + (long)b * DIM * SEQ;
      float* Op = out + (long)b * SEQ * DIM;
      gemm_nt_kernel<2><<<(SEQ / 128) * (SEQ / 128), 256, 0, stream>>>(
          Qp, Kp, S, DIM, DIM, SEQ, DIM, SEQ / 128, 0, 1, scale);
      softmax_kernel<<<SEQ, 256, 0, stream>>>(S);
      gemm_nt_kernel<2><<<(SEQ / 128) * (DIM / 128), 256, 0, stream>>>(
          (const unsigned short*)S, Vp, Op, 2 * SEQ, SEQ, DIM, SEQ, DIM / 128,
          0, 2, 1.0f);
    }
  }
}

// Round 2
// 582.476 us; speedup vs baseline: 1.1604x; 1.1604x over previous
//
#include <hip/hip_runtime.h>
#include <hip/hip_bf16.h>

// SingleHeadAttention: B=4, S=4096, D=1024, fp32 in/out, causal, interleaved RoPE.
// R2: BK=64 + XOR-swizzled LDS (conflict-free ds_read_b128, pre-swizzled global src),
//     fused Q+K projection (X staged once, 2 acc sets), XCD-bijective block swizzle,
//     vectorized softmax, fused weight cvt. Sync structure unchanged (2-barrier loop).

#define SEQ 4096
#define DIM 1024
#define NBATCH 4

typedef short bf16x8 __attribute__((ext_vector_type(8)));
typedef float f32x4 __attribute__((ext_vector_type(4)));

__device__ __forceinline__ unsigned short f2bf(float f) {
  unsigned int u = __float_as_uint(f);
  u += 0x7FFFu + ((u >> 16) & 1u);   // RNE
  return (unsigned short)(u >> 16);
}

// bijective XCD swizzle (nwg % 8 == 0 for all our grids)
__device__ __forceinline__ int xcd_swz(int bid, int nwg) {
  return (bid & 7) * (nwg >> 3) + (bid >> 3);
}

__device__ __forceinline__ void gll16(const unsigned short* g, unsigned short* l) {
  __builtin_amdgcn_global_load_lds(
      (const __attribute__((address_space(1))) void*)g,
      (__attribute__((address_space(3))) void*)l, 16, 0, 0);
}

__global__ __launch_bounds__(256) void cvt_bf16_kernel(const float* __restrict__ in,
                                                       unsigned short* __restrict__ out,
                                                       int n4) {
  int stride = gridDim.x * blockDim.x;
  for (int j = blockIdx.x * blockDim.x + threadIdx.x; j < n4; j += stride) {
    float4 v = ((const float4*)in)[j];
    ushort4 o;
    o.x = f2bf(v.x); o.y = f2bf(v.y); o.z = f2bf(v.z); o.w = f2bf(v.w);
    ((ushort4*)out)[j] = o;
  }
}

// 3 weights (each DIM*DIM) -> contiguous bf16 dst
__global__ __launch_bounds__(256) void cvt_w3_kernel(const float* __restrict__ a,
                                                     const float* __restrict__ b,
                                                     const float* __restrict__ c,
                                                     unsigned short* __restrict__ dst) {
  const int n4 = DIM * DIM / 4;
  int stride = gridDim.x * blockDim.x;
  for (int j = blockIdx.x * blockDim.x + threadIdx.x; j < 3 * n4; j += stride) {
    const float* src = j < n4 ? a : (j < 2 * n4 ? b : c);
    const int off = j < n4 ? j : (j < 2 * n4 ? j - n4 : j - 2 * n4);
    float4 v = ((const float4*)src)[off];
    ushort4 o;
    o.x = f2bf(v.x); o.y = f2bf(v.y); o.z = f2bf(v.z); o.w = f2bf(v.w);
    ((ushort4*)dst)[j] = o;
  }
}

// RoPE epilogue: pairs (2i,2i+1) are adjacent lanes (col parity == lane parity)
__device__ __forceinline__ void rope_store(const f32x4 (&acc)[4][4], unsigned short* C,
                                           int rbase, int cbase, int ldc) {
#pragma unroll
  for (int nj = 0; nj < 4; ++nj) {
    const int col = cbase + nj * 16;
    // inv_freq = 10000^(-(col>>1)/512); log2(10000)/512 = 0.025952563241307517
    const float invfreq = exp2f(-0.025952563241307517f * (float)(col >> 1));
    const bool odd = (col & 1) != 0;
#pragma unroll
    for (int mi = 0; mi < 4; ++mi)
#pragma unroll
      for (int r = 0; r < 4; ++r) {
        const int row = rbase + mi * 16 + r;
        const float v = acc[mi][nj][r];
        const float p = __shfl_xor(v, 1, 64);   // partner column (col^1), same row
        const float ang = (float)(row & (SEQ - 1)) * invfreq;
        const float sn = __sinf(ang), cs = __cosf(ang);
        C[(long)row * ldc + col] = f2bf(odd ? (v * cs + p * sn) : (v * cs - p * sn));
      }
  }
}

// Fused Q+K projection: C_q = X Wq^T (+RoPE), C_k = X Wk^T (+RoPE).
// 128x128 tile, BK=64, swizzled LDS, X staged once per K-step.
__global__ __launch_bounds__(256, 2) void qk_proj_kernel(
    const unsigned short* __restrict__ X,
    const unsigned short* __restrict__ Wq,
    const unsigned short* __restrict__ Wk,
    unsigned short* __restrict__ Q,
    unsigned short* __restrict__ Ko) {
  const int bid = xcd_swz(blockIdx.x, gridDim.x);
  const int mt = bid >> 3, nt = bid & 7;     // 128 x 8 tiles
  const int m0 = mt * 128, n0 = nt * 128;

  __shared__ unsigned short sX[128 * 64];
  __shared__ unsigned short sQ[128 * 64];
  __shared__ unsigned short sK[128 * 64];

  const int t = threadIdx.x, w = t >> 6, l = t & 63;
  const int wm = w >> 1, wn = w & 1;
  const int srow = l >> 3;                   // row within 8-row chunk
  const int scol = ((l & 7) ^ srow) * 8;     // pre-swizzled k-slot (elements)
  const int frow = l & 15;

  f32x4 cq[4][4] = {}, ck[4][4] = {};

  for (int k0 = 0; k0 < DIM; k0 += 64) {
#pragma unroll
    for (int j = 0; j < 4; ++j) {
      const int c = 4 * w + j;               // 1KiB chunk (8 rows x 128B)
      const int gr = c * 8 + srow;
      gll16(X  + (long)(m0 + gr) * DIM + k0 + scol, &sX[c * 512]);
      gll16(Wq + (long)(n0 + gr) * DIM + k0 + scol, &sQ[c * 512]);
      gll16(Wk + (long)(n0 + gr) * DIM + k0 + scol, &sK[c * 512]);
    }
    __syncthreads();
#pragma unroll
    for (int kk = 0; kk < 2; ++kk) {
      const int slot = (l >> 4) + 4 * kk;
      bf16x8 xa[4], bb[4];
#pragma unroll
      for (int i = 0; i < 4; ++i) {
        const int row = wm * 64 + i * 16 + frow;
        xa[i] = *(const bf16x8*)(&sX[row * 64 + ((slot ^ (row & 7)) << 3)]);
      }
#pragma unroll
      for (int i = 0; i < 4; ++i) {
        const int row = wn * 64 + i * 16 + frow;
        bb[i] = *(const bf16x8*)(&sQ[row * 64 + ((slot ^ (row & 7)) << 3)]);
      }
#pragma unroll
      for (int mi = 0; mi < 4; ++mi)
#pragma unroll
        for (int nj = 0; nj < 4; ++nj)
          cq[mi][nj] = __builtin_amdgcn_mfma_f32_16x16x32_bf16(xa[mi], bb[nj], cq[mi][nj], 0, 0, 0);
#pragma unroll
      for (int i = 0; i < 4; ++i) {
        const int row = wn * 64 + i * 16 + frow;
        bb[i] = *(const bf16x8*)(&sK[row * 64 + ((slot ^ (row & 7)) << 3)]);
      }
#pragma unroll
      for (int mi = 0; mi < 4; ++mi)
#pragma unroll
        for (int nj = 0; nj < 4; ++nj)
          ck[mi][nj] = __builtin_amdgcn_mfma_f32_16x16x32_bf16(xa[mi], bb[nj], ck[mi][nj], 0, 0, 0);
    }
    __syncthreads();
  }

  // C/D layout: col = lane&15, row = (lane>>4)*4 + reg
  const int rbase = m0 + wm * 64 + (l >> 4) * 4;
  const int cbase = n0 + wn * 64 + frow;
  rope_store(cq, Q, rbase, cbase, DIM);
  rope_store(ck, Ko, rbase, cbase, DIM);
}

// Generic NT GEMM: C[m][n] = sum_k A[m][k]*B[n][k]. 128x128 tile, BK=64, swizzled LDS.
// mode: 0 none, 1 causal tile skip (scores), 2 causal k-limit (PV)
// EPI:  1 = V^T-layout bf16 scatter, 2 = fp32 * scale
template <int EPI>
__global__ __launch_bounds__(256, 2) void gemm_nt_kernel(
    const unsigned short* __restrict__ A,
    const unsigned short* __restrict__ B,
    void* __restrict__ Cv,
    int lda, int ldb, int ldc,
    int K, int nTilesN, long bstrideB,
    int mode, float scale) {
  const int bid = xcd_swz(blockIdx.x, gridDim.x);
  const int mt = bid / nTilesN;
  const int nt = bid % nTilesN;
  const int m0 = mt * 128, n0 = nt * 128;
  const int mrow = m0 & (SEQ - 1);
  if (mode == 1 && n0 > mrow + 127) return;
  const int Keff = (mode == 2 && mrow + 128 < K) ? (mrow + 128) : K;
  const unsigned short* Bp = B + (long)(m0 >> 12) * bstrideB;

  __shared__ unsigned short sA[128 * 64];
  __shared__ unsigned short sB[128 * 64];

  const int t = threadIdx.x, w = t >> 6, l = t & 63;
  const int wm = w >> 1, wn = w & 1;
  const int srow = l >> 3;
  const int scol = ((l & 7) ^ srow) * 8;
  const int frow = l & 15;

  f32x4 acc[4][4] = {};

  for (int k0 = 0; k0 < Keff; k0 += 64) {
#pragma unroll
    for (int j = 0; j < 4; ++j) {
      const int c = 4 * w + j;
      const int gr = c * 8 + srow;
      gll16(A  + (long)(m0 + gr) * lda + k0 + scol, &sA[c * 512]);
      gll16(Bp + (long)(n0 + gr) * ldb + k0 + scol, &sB[c * 512]);
    }
    __syncthreads();
#pragma unroll
    for (int kk = 0; kk < 2; ++kk) {
      const int slot = (l >> 4) + 4 * kk;
      bf16x8 av[4], bv[4];
#pragma unroll
      for (int i = 0; i < 4; ++i) {
        const int row = wm * 64 + i * 16 + frow;
        av[i] = *(const bf16x8*)(&sA[row * 64 + ((slot ^ (row & 7)) << 3)]);
      }
#pragma unroll
      for (int i = 0; i < 4; ++i) {
        const int row = wn * 64 + i * 16 + frow;
        bv[i] = *(const bf16x8*)(&sB[row * 64 + ((slot ^ (row & 7)) << 3)]);
      }
#pragma unroll
      for (int mi = 0; mi < 4; ++mi)
#pragma unroll
        for (int nj = 0; nj < 4; ++nj)
          acc[mi][nj] = __builtin_amdgcn_mfma_f32_16x16x32_bf16(av[mi], bv[nj], acc[mi][nj], 0, 0, 0);
    }
    __syncthreads();
  }

  const int rbase = m0 + wm * 64 + (l >> 4) * 4;
  const int cbase = n0 + wn * 64 + frow;

  if (EPI == 2) {
    float* C = (float*)Cv;
#pragma unroll
    for (int mi = 0; mi < 4; ++mi)
#pragma unroll
      for (int nj = 0; nj < 4; ++nj)
#pragma unroll
        for (int r = 0; r < 4; ++r)
          C[(long)(rbase + mi * 16 + r) * ldc + (cbase + nj * 16)] = acc[mi][nj][r] * scale;
  } else {
    // write C[row=e][col=token] into VT[b][e][s]
    unsigned short* C = (unsigned short*)Cv;
#pragma unroll
    for (int mi = 0; mi < 4; ++mi)
#pragma unroll
      for (int nj = 0; nj < 4; ++nj)
#pragma unroll
        for (int r = 0; r < 4; ++r) {
          const int row = rbase + mi * 16 + r;
          const int col = cbase + nj * 16;
          C[(long)(col >> 12) * (DIM * SEQ) + (long)row * SEQ + (col & (SEQ - 1))] =
              f2bf(acc[mi][nj][r]);
        }
  }
}

// One block per row; vectorized float4/ushort4; P bf16 in place (row stride 8192 bf16).
__global__ __launch_bounds__(256) void softmax_kernel(float* __restrict__ S) {
  const int q = blockIdx.x & (SEQ - 1);
  float* row = S + (long)blockIdx.x * SEQ;
  const int len = q + 1;
  const int len4 = len >> 2;
  const int kpad = (q & ~127) + 128;
  __shared__ __align__(16) float buf[SEQ];
  __shared__ float red[8];
  const int t = threadIdx.x;

  float lmax = -3.0e38f;
  for (int i = t; i < len4; i += 256) {
    float4 v = ((const float4*)row)[i];
    ((float4*)buf)[i] = v;
    lmax = fmaxf(lmax, fmaxf(fmaxf(v.x, v.y), fmaxf(v.z, v.w)));
  }
  for (int k = len4 * 4 + t; k < len; k += 256) {
    const float v = row[k];
    buf[k] = v;
    lmax = fmaxf(lmax, v);
  }
#pragma unroll
  for (int o = 32; o; o >>= 1) lmax = fmaxf(lmax, __shfl_xor(lmax, o, 64));
  if ((t & 63) == 0) red[t >> 6] = lmax;
  __syncthreads();
  const float m = fmaxf(fmaxf(red[0], red[1]), fmaxf(red[2], red[3]));

  float lsum = 0.f;
  for (int i = t; i < len4; i += 256) {
    float4 v = ((float4*)buf)[i];
    v.x = __expf(v.x - m); v.y = __expf(v.y - m);
    v.z = __expf(v.z - m); v.w = __expf(v.w - m);
    ((float4*)buf)[i] = v;
    lsum += (v.x + v.y) + (v.z + v.w);
  }
  for (int k = len4 * 4 + t; k < len; k += 256) {
    const float e = __expf(buf[k] - m);
    buf[k] = e;
    lsum += e;
  }
#pragma unroll
  for (int o = 32; o; o >>= 1) lsum += __shfl_xor(lsum, o, 64);
  if ((t & 63) == 0) red[4 + (t >> 6)] = lsum;
  __syncthreads();
  const float inv = 1.0f / (red[4] + red[5] + red[6] + red[7]);

  unsigned short* prow = (unsigned short*)row;
  for (int i = t; i < len4; i += 256) {
    float4 v = ((const float4*)buf)[i];
    ushort4 o;
    o.x = f2bf(v.x * inv); o.y = f2bf(v.y * inv);
    o.z = f2bf(v.z * inv); o.w = f2bf(v.w * inv);
    ((ushort4*)prow)[i] = o;
  }
  for (int k = len4 * 4 + t; k < len; k += 256) prow[k] = f2bf(buf[k] * inv);
  for (int k = len + t; k < kpad; k += 256) prow[k] = 0;
}

extern "C" void kernel_launch(void* const* d_in, const int* in_sizes, int n_in,
                              void* d_out, int out_size, void* d_ws, size_t ws_size,
                              hipStream_t stream) {
  (void)in_sizes; (void)n_in; (void)out_size;
  const float* x  = (const float*)d_in[0];
  const float* wq = (const float*)d_in[1];
  const float* wk = (const float*)d_in[2];
  const float* wv = (const float*)d_in[3];
  float* out = (float*)d_out;

  const long NTOK = (long)SEQ * NBATCH;          // 16384
  unsigned short* xb  = (unsigned short*)d_ws;   // [16384][1024] bf16
  unsigned short* wqb = xb + NTOK * DIM;         // wq|wk|wv contiguous
  unsigned short* wkb = wqb + DIM * DIM;
  unsigned short* wvb = wkb + DIM * DIM;
  unsigned short* Qb  = wvb + DIM * DIM;         // [16384][1024] bf16 (RoPE'd)
  unsigned short* Kb  = Qb + NTOK * DIM;
  unsigned short* VT  = Kb + NTOK * DIM;         // [4][1024][4096] bf16
  float* S = (float*)(VT + NTOK * DIM);          // scores / P (bf16 in place)

  const size_t base_bytes = 2ull * (4ull * NTOK * DIM + 3ull * DIM * DIM);
  const bool full = ws_size >= base_bytes + 4ull * NBATCH * SEQ * SEQ;

  // fp32 -> bf16
  cvt_bf16_kernel<<<2048, 256, 0, stream>>>(x, xb, (int)(NTOK * DIM / 4));
  cvt_w3_kernel<<<1024, 256, 0, stream>>>(wq, wk, wv, wqb);

  const float scale = 0.03125f;                  // 1/sqrt(1024)

  // projections: Q,K fused (+RoPE); V transposed
  qk_proj_kernel<<<128 * 8, 256, 0, stream>>>(xb, wqb, wkb, Qb, Kb);
  gemm_nt_kernel<1><<<8 * 128, 256, 0, stream>>>(
      wvb, xb, VT, DIM, DIM, SEQ, DIM, 128, 0, 0, 0.f);

  if (full) {
    gemm_nt_kernel<2><<<128 * 32, 256, 0, stream>>>(
        Qb, Kb, S, DIM, DIM, SEQ, DIM, 32, (long)SEQ * DIM, 1, scale);
    softmax_kernel<<<(int)NTOK, 256, 0, stream>>>(S);
    gemm_nt_kernel<2><<<128 * 8, 256, 0, stream>>>(
        (const unsigned short*)S, VT, out, 2 * SEQ, SEQ, DIM, SEQ, 8,
        (long)DIM * SEQ, 2, 1.0f);
  } else {
    for (int b = 0; b < NBATCH; ++b) {
      const unsigned short* Qp = Qb + (long)b * SEQ * DIM;
      const unsigned short* Kp = Kb + (long)b * SEQ * DIM;
      const unsigned short* Vp = VT + (long)b * DIM * SEQ;
      float* Op = out + (long)b * SEQ * DIM;
      gemm_nt_kernel<2><<<32 * 32, 256, 0, stream>>>(
          Qp, Kp, S, DIM, DIM, SEQ, DIM, 32, 0, 1, scale);
      softmax_kernel<<<SEQ, 256, 0, stream>>>(S);
      gemm_nt_kernel<2><<<32 * 8, 256, 0, stream>>>(
          (const unsigned short*)S, Vp, Op, 2 * SEQ, SEQ, DIM, SEQ, 8,
          0, 2, 1.0f);
    }
  }
}